// Round 2
// baseline (687.396 us; speedup 1.0000x reference)
//
#include <hip/hip_runtime.h>
#include <hip/hip_bf16.h>
#include <stdint.h>

// Problem constants (B=4, T=2048, D=H=1024, E=8, topn=2)
#define TOKENS   8192
#define DDIM     1024
#define EXPERTS  8
#define NSLOT    (TOKENS * 2)   // every token picks exactly 2 experts

typedef __bf16 bf16x8_t __attribute__((ext_vector_type(8)));
typedef __bf16 bf16x4_t __attribute__((ext_vector_type(4)));
typedef float  f32x4_t  __attribute__((ext_vector_type(4)));

// ---------------------------------------------------------------------------
// async global->LDS, 16B per lane; LDS dest must be wave-uniform base (HW adds
// lane*16).
__device__ __forceinline__ void gl_lds16(const void* g, void* l) {
  __builtin_amdgcn_global_load_lds(
      (const __attribute__((address_space(1))) void*)g,
      (__attribute__((address_space(3))) void*)l, 16, 0, 0);
}

// ---------------------------------------------------------------------------
// fp32 -> bf16 elementwise convert (x)
__global__ __launch_bounds__(256) void cvt_bf16_k(const float* __restrict__ in,
                                                  __bf16* __restrict__ out,
                                                  int n4) {
  int i = blockIdx.x * 256 + threadIdx.x;
  if (i < n4) {
    float4 v = ((const float4*)in)[i];
    bf16x4_t o = {(__bf16)v.x, (__bf16)v.y, (__bf16)v.z, (__bf16)v.w};
    ((bf16x4_t*)out)[i] = o;
  }
}

// ---------------------------------------------------------------------------
// Weight transpose + convert: w[e][k][n] fp32 -> wT[e][n][k] bf16.
// 32x32 tile through LDS. Read coalesced (128B/row); write is 2B/lane along k
// (64B segments) -- acceptable for a one-shot prep kernel.
// tile[k][n] padded +1: write-phase read tile[tx][r] is conflict-free.
__global__ void twt_k(const float* __restrict__ w, __bf16* __restrict__ wT) {
  __shared__ float tile[32][33];
  const int kb = blockIdx.x * 32, nb = blockIdx.y * 32;
  const size_t ebase = (size_t)blockIdx.z << 20;  // e * 1024*1024
  const int tx = threadIdx.x, ty = threadIdx.y;
  const float* src = w + ebase;
#pragma unroll
  for (int r = ty; r < 32; r += 8)
    tile[r][tx] = src[(size_t)(kb + r) * 1024 + nb + tx];
  __syncthreads();
  __bf16* dst = wT + ebase;
#pragma unroll
  for (int r = ty; r < 32; r += 8)
    dst[(size_t)(nb + r) * 1024 + kb + tx] = (__bf16)tile[tx][r];
}

// ---------------------------------------------------------------------------
// Gating: one wave per token. fp32 logits, top-2 (first-occurrence ties like
// jax top_k), weights = softmax over the two top logits (L1-renorm of masked
// softmax cancels the full denominator).
__global__ __launch_bounds__(256) void gate_k(
    const float* __restrict__ x, const float* __restrict__ gw,
    const float* __restrict__ gb, int* __restrict__ cnt,
    int* __restrict__ top_i, float* __restrict__ top_w) {
  const int t = blockIdx.x * 4 + (threadIdx.x >> 6);
  const int lane = threadIdx.x & 63;
  const float* xr = x + (size_t)t * DDIM;
  float acc[EXPERTS];
#pragma unroll
  for (int e = 0; e < EXPERTS; ++e) acc[e] = 0.f;
  for (int d = lane; d < DDIM; d += 64) {
    const float xv = xr[d];
    const float4 g0 = ((const float4*)gw)[d * 2];
    const float4 g1 = ((const float4*)gw)[d * 2 + 1];
    acc[0] += xv * g0.x; acc[1] += xv * g0.y;
    acc[2] += xv * g0.z; acc[3] += xv * g0.w;
    acc[4] += xv * g1.x; acc[5] += xv * g1.y;
    acc[6] += xv * g1.z; acc[7] += xv * g1.w;
  }
#pragma unroll
  for (int e = 0; e < EXPERTS; ++e)
    for (int s = 32; s > 0; s >>= 1) acc[e] += __shfl_down(acc[e], s);
  if (lane == 0) {
#pragma unroll
    for (int e = 0; e < EXPERTS; ++e) acc[e] += gb[e];
    int i1 = 0;
    for (int e = 1; e < EXPERTS; ++e)
      if (acc[e] > acc[i1]) i1 = e;
    int i2 = (i1 == 0) ? 1 : 0;
    for (int e = 0; e < EXPERTS; ++e)
      if (e != i1 && acc[e] > acc[i2]) i2 = e;
    const float r = expf(acc[i2] - acc[i1]);  // <= 1
    const float wA = 1.f / (1.f + r);
    const float wB = r / (1.f + r);
    top_i[t * 2] = i1; top_i[t * 2 + 1] = i2;
    top_w[t * 2] = wA; top_w[t * 2 + 1] = wB;
    atomicAdd(&cnt[i1], 1);
    atomicAdd(&cnt[i2], 1);
  }
}

// Exclusive prefix sum over 8 expert counts.
__global__ void scan_k(const int* __restrict__ cnt, int* __restrict__ eoff,
                       int* __restrict__ cursor) {
  if (threadIdx.x == 0) {
    int s = 0;
    for (int e = 0; e < EXPERTS; ++e) {
      eoff[e] = s; cursor[e] = s; s += cnt[e];
    }
    eoff[EXPERTS] = s;  // == NSLOT
  }
}

// Scatter tokens into compact per-expert slot lists.
__global__ void scatter_k(const int* __restrict__ top_i, int* cursor,
                          int* __restrict__ tok_list,
                          int* __restrict__ slot_of) {
  const int t = blockIdx.x * 256 + threadIdx.x;
#pragma unroll
  for (int j = 0; j < 2; ++j) {
    const int e = top_i[t * 2 + j];
    const int s = atomicAdd(&cursor[e], 1);
    tok_list[s] = t;
    slot_of[t * 2 + j] = s;
  }
}

// ---------------------------------------------------------------------------
// Per-expert GEMM, m97-style: 128x128 tile, BK=32, mfma_f32_16x16x32_bf16,
// global_load_lds(16B) staging, LDS tiles stored k-contiguous.
//   C[m][n] = act( sum_k A[row(m)][k] * W[e][n][k] + bias[e][n] )
// GATHER: A row = tok_list[off+m] (x rows); else A row = off+m (h buffers).
template <int GATHER, int LEAKY, int OUTBF>
__global__ __launch_bounds__(256) void moe_gemm(
    const __bf16* __restrict__ A, const int* __restrict__ tok,
    const __bf16* __restrict__ W, const float* __restrict__ bias,
    const int* __restrict__ eoff, __bf16* __restrict__ outb,
    float* __restrict__ outf) {
  const int e = blockIdx.z;
  const int off = eoff[e];
  const int ne = eoff[e + 1] - off;
  const int m0 = blockIdx.y * 128;
  if (m0 >= ne) return;
  const int n0 = blockIdx.x * 128;

  __shared__ __align__(16) __bf16 As[128 * 32];  // [row][k]
  __shared__ __align__(16) __bf16 Bs[128 * 32];  // [n][k]

  const int tid = threadIdx.x;
  const int lane = tid & 63;
  const int wid = tid >> 6;
  const int wm = wid >> 1, wn = wid & 1;
  const int ln = lane & 15, quad = lane >> 4;

  // Staging pointers: chunk c covers tile row c>>2, k-chunk (c&3)*8.
  const __bf16* aptr[2];
  const __bf16* bptr[2];
  __bf16* alds[2];
  __bf16* blds[2];
#pragma unroll
  for (int j = 0; j < 2; ++j) {
    const int c = (wid * 2 + j) * 64 + lane;  // 0..511
    const int row = c >> 2, kc = c & 3;
    int r = m0 + row;
    if (r >= ne) r = m0;  // clamp: garbage rows computed but never stored
    const long arow = GATHER ? (long)tok[off + r] : (long)(off + r);
    aptr[j] = A + arow * DDIM + kc * 8;
    alds[j] = (__bf16*)As + (wid * 2 + j) * 512;
    bptr[j] = W + ((long)e << 20) + (long)(n0 + row) * 1024 + kc * 8;
    blds[j] = (__bf16*)Bs + (wid * 2 + j) * 512;
  }

  const f32x4_t vzero = {0.f, 0.f, 0.f, 0.f};
  f32x4_t acc[4][4];
#pragma unroll
  for (int i = 0; i < 4; ++i)
#pragma unroll
    for (int j = 0; j < 4; ++j) acc[i][j] = vzero;

  for (int kt = 0; kt < 32; ++kt) {
    const int k0 = kt * 32;
    __syncthreads();  // previous iter's LDS reads done
    gl_lds16(aptr[0] + k0, alds[0]);
    gl_lds16(aptr[1] + k0, alds[1]);
    gl_lds16(bptr[0] + k0, blds[0]);
    gl_lds16(bptr[1] + k0, blds[1]);
    __syncthreads();  // drains vmcnt: staged data visible

    bf16x8_t aF[4], bF[4];
#pragma unroll
    for (int i = 0; i < 4; ++i)
      aF[i] = *(const bf16x8_t*)(As + (wm * 64 + i * 16 + ln) * 32 + quad * 8);
#pragma unroll
    for (int j = 0; j < 4; ++j)
      bF[j] = *(const bf16x8_t*)(Bs + (wn * 64 + j * 16 + ln) * 32 + quad * 8);
#pragma unroll
    for (int i = 0; i < 4; ++i)
#pragma unroll
      for (int j = 0; j < 4; ++j)
        acc[i][j] = __builtin_amdgcn_mfma_f32_16x16x32_bf16(aF[i], bF[j],
                                                            acc[i][j], 0, 0, 0);
  }

  // Epilogue. C/D layout: col = lane&15, row = quad*4 + reg.
  const float* bs = bias + e * 1024;
#pragma unroll
  for (int i = 0; i < 4; ++i) {
    const int rloc = wm * 64 + i * 16 + quad * 4;
#pragma unroll
    for (int j = 0; j < 4; ++j) {
      const int col = n0 + wn * 64 + j * 16 + ln;
      const float bv = bs[col];
#pragma unroll
      for (int r = 0; r < 4; ++r) {
        const int m = m0 + rloc + r;
        if (m < ne) {
          float v = acc[i][j][r] + bv;
          if (LEAKY) v = (v >= 0.f) ? v : 0.01f * v;
          if (OUTBF)
            outb[(size_t)(off + m) * 1024 + col] = (__bf16)v;
          else
            outf[(size_t)(off + m) * 1024 + col] = v;
        }
      }
    }
  }
}

// ---------------------------------------------------------------------------
// Final combine: out[t] = wA*eo[slotA] + wB*eo[slotB]
__global__ __launch_bounds__(256) void combine_k(
    const float* __restrict__ eo, const int* __restrict__ slot_of,
    const float* __restrict__ top_w, float* __restrict__ out) {
  const int t = blockIdx.x;
  const int s1 = slot_of[t * 2], s2 = slot_of[t * 2 + 1];
  const float w1 = top_w[t * 2], w2 = top_w[t * 2 + 1];
  const float4 a = ((const float4*)(eo + (size_t)s1 * DDIM))[threadIdx.x];
  const float4 b = ((const float4*)(eo + (size_t)s2 * DDIM))[threadIdx.x];
  float4 o;
  o.x = w1 * a.x + w2 * b.x;
  o.y = w1 * a.y + w2 * b.y;
  o.z = w1 * a.z + w2 * b.z;
  o.w = w1 * a.w + w2 * b.w;
  ((float4*)(out + (size_t)t * DDIM))[threadIdx.x] = o;
}

// ---------------------------------------------------------------------------
extern "C" void kernel_launch(void* const* d_in, const int* in_sizes, int n_in,
                              void* d_out, int out_size, void* d_ws,
                              size_t ws_size, hipStream_t stream) {
  (void)in_sizes; (void)n_in; (void)out_size; (void)ws_size;
  const float* x  = (const float*)d_in[0];
  const float* gw = (const float*)d_in[1];
  const float* gb = (const float*)d_in[2];
  const float* w1 = (const float*)d_in[3];
  const float* b1 = (const float*)d_in[4];
  const float* w2 = (const float*)d_in[5];
  const float* b2 = (const float*)d_in[6];
  const float* w3 = (const float*)d_in[7];
  const float* b3 = (const float*)d_in[8];
  float* out = (float*)d_out;

  // Workspace carve-up (~202 MB total).
  uint8_t* p = (uint8_t*)d_ws;
  auto alloc = [&](size_t b) {
    uint8_t* r = p;
    p += (b + 255) & ~(size_t)255;
    return r;
  };
  int*    cnt      = (int*)alloc(4 * EXPERTS);
  int*    cursor   = (int*)alloc(4 * EXPERTS);
  int*    eoff     = (int*)alloc(4 * (EXPERTS + 1));
  int*    top_i    = (int*)alloc(4ull * TOKENS * 2);
  float*  top_w    = (float*)alloc(4ull * TOKENS * 2);
  int*    slot_of  = (int*)alloc(4ull * TOKENS * 2);
  int*    tok_list = (int*)alloc(4ull * NSLOT);
  __bf16* xbf      = (__bf16*)alloc(2ull * TOKENS * DDIM);
  __bf16* w1T      = (__bf16*)alloc(2ull * EXPERTS * 1024 * 1024);
  __bf16* w2T      = (__bf16*)alloc(2ull * EXPERTS * 1024 * 1024);
  __bf16* w3T      = (__bf16*)alloc(2ull * EXPERTS * 1024 * 1024);
  __bf16* h1       = (__bf16*)alloc(2ull * NSLOT * 1024);
  __bf16* h2       = (__bf16*)alloc(2ull * NSLOT * 1024);
  float*  eo       = (float*)alloc(4ull * NSLOT * 1024);

  hipMemsetAsync(cnt, 0, 4 * EXPERTS, stream);

  cvt_bf16_k<<<(TOKENS * DDIM / 4 + 255) / 256, 256, 0, stream>>>(
      x, xbf, TOKENS * DDIM / 4);
  twt_k<<<dim3(32, 32, EXPERTS), dim3(32, 8), 0, stream>>>(w1, w1T);
  twt_k<<<dim3(32, 32, EXPERTS), dim3(32, 8), 0, stream>>>(w2, w2T);
  twt_k<<<dim3(32, 32, EXPERTS), dim3(32, 8), 0, stream>>>(w3, w3T);
  gate_k<<<TOKENS / 4, 256, 0, stream>>>(x, gw, gb, cnt, top_i, top_w);
  scan_k<<<1, 64, 0, stream>>>(cnt, eoff, cursor);
  scatter_k<<<TOKENS / 256, 256, 0, stream>>>(top_i, cursor, tok_list, slot_of);

  // 3 expert-parallel GEMM layers; grid.y sized for worst-case routing.
  moe_gemm<1, 1, 1><<<dim3(8, 64, EXPERTS), 256, 0, stream>>>(
      xbf, tok_list, w1T, b1, eoff, h1, nullptr);
  moe_gemm<0, 1, 1><<<dim3(8, 64, EXPERTS), 256, 0, stream>>>(
      h1, nullptr, w2T, b2, eoff, h2, nullptr);
  moe_gemm<0, 0, 0><<<dim3(8, 64, EXPERTS), 256, 0, stream>>>(
      h2, nullptr, w3T, b3, eoff, nullptr, eo);

  combine_k<<<TOKENS, 256, 0, stream>>>(eo, slot_of, top_w, out);
}

// Round 3
// 440.591 us; speedup vs baseline: 1.5602x; 1.5602x over previous
//
#include <hip/hip_runtime.h>
#include <hip/hip_bf16.h>
#include <stdint.h>

// Problem constants (B=4, T=2048, D=H=1024, E=8, topn=2)
#define TOKENS   8192
#define DDIM     1024
#define EXPERTS  8
#define NSLOT    (TOKENS * 2)   // every token picks exactly 2 experts

typedef __bf16 bf16x8_t __attribute__((ext_vector_type(8)));
typedef __bf16 bf16x4_t __attribute__((ext_vector_type(4)));
typedef float  f32x4_t  __attribute__((ext_vector_type(4)));

// ---------------------------------------------------------------------------
// async global->LDS, 16B per lane; LDS dest must be wave-uniform base (HW adds
// lane*16).
__device__ __forceinline__ void gl_lds16(const void* g, void* l) {
  __builtin_amdgcn_global_load_lds(
      (const __attribute__((address_space(1))) void*)g,
      (__attribute__((address_space(3))) void*)l, 16, 0, 0);
}

// ---------------------------------------------------------------------------
// Weight transpose + convert: w[e][k][n] fp32 -> wT[e][n][k] bf16.
// k-tile 64, n-tile 32. Reads 128B/row coalesced; writes packed 2xbf16 (4B)
// -> 128B per wave row. tile padded +1 col: phase-2 read tile[2tx][r] has
// word-stride 66 -> 2-way bank conflict (free, m136).
__global__ void twt_k(const float* __restrict__ w, __bf16* __restrict__ wT) {
  __shared__ float tile[64][33];
  const int kb = blockIdx.x * 64, nb = blockIdx.y * 32;
  const size_t ebase = (size_t)blockIdx.z << 20;  // e * 1024*1024
  const int tx = threadIdx.x, ty = threadIdx.y;   // 32 x 8
  const float* src = w + ebase;
#pragma unroll
  for (int r = ty; r < 64; r += 8)
    tile[r][tx] = src[(size_t)(kb + r) * 1024 + nb + tx];
  __syncthreads();
  __bf16* dst = wT + ebase;
#pragma unroll
  for (int r = ty; r < 32; r += 8) {
    union { __bf16 h[2]; unsigned u; } pk;
    pk.h[0] = (__bf16)tile[2 * tx][r];
    pk.h[1] = (__bf16)tile[2 * tx + 1][r];
    *(unsigned*)(dst + (size_t)(nb + r) * 1024 + kb + 2 * tx) = pk.u;
  }
}

// ---------------------------------------------------------------------------
// Gating + x->bf16 convert fused: one wave per token. NO atomics (the round-2
// 200us stall was 16K same-cacheline atomicAdds).
// Weights = softmax over the two top logits (L1-renorm cancels denominator).
__global__ __launch_bounds__(256) void gate_k(
    const float* __restrict__ x, const float* __restrict__ gw,
    const float* __restrict__ gb, __bf16* __restrict__ xbf,
    int* __restrict__ top_i, float* __restrict__ top_w) {
  const int t = blockIdx.x * 4 + (threadIdx.x >> 6);
  const int lane = threadIdx.x & 63;
  const float* xr = x + (size_t)t * DDIM;
  __bf16* xo = xbf + (size_t)t * DDIM;
  float acc[EXPERTS];
#pragma unroll
  for (int e = 0; e < EXPERTS; ++e) acc[e] = 0.f;
  for (int d = lane; d < DDIM; d += 64) {
    const float xv = xr[d];
    xo[d] = (__bf16)xv;  // fused convert
    const float4 g0 = ((const float4*)gw)[d * 2];
    const float4 g1 = ((const float4*)gw)[d * 2 + 1];
    acc[0] += xv * g0.x; acc[1] += xv * g0.y;
    acc[2] += xv * g0.z; acc[3] += xv * g0.w;
    acc[4] += xv * g1.x; acc[5] += xv * g1.y;
    acc[6] += xv * g1.z; acc[7] += xv * g1.w;
  }
#pragma unroll
  for (int e = 0; e < EXPERTS; ++e)
    for (int s = 32; s > 0; s >>= 1) acc[e] += __shfl_down(acc[e], s);
  if (lane == 0) {
#pragma unroll
    for (int e = 0; e < EXPERTS; ++e) acc[e] += gb[e];
    int i1 = 0;
    for (int e = 1; e < EXPERTS; ++e)
      if (acc[e] > acc[i1]) i1 = e;
    int i2 = (i1 == 0) ? 1 : 0;
    for (int e = 0; e < EXPERTS; ++e)
      if (e != i1 && acc[e] > acc[i2]) i2 = e;
    const float r = expf(acc[i2] - acc[i1]);  // <= 1
    const float wA = 1.f / (1.f + r);
    const float wB = r / (1.f + r);
    top_i[t * 2] = i1; top_i[t * 2 + 1] = i2;
    top_w[t * 2] = wA; top_w[t * 2 + 1] = wB;
  }
}

// ---------------------------------------------------------------------------
// Routing plan: ONE block, 1024 threads. Stable counting-sort of the 16384
// (token,expert) entries by expert id. Zero global atomics, deterministic.
// Per-thread histogram byte-packed in u64 (<=16 per counter); intra-wave
// exclusive scan via shfl; cross-wave scan by thread 0; per-thread bases
// parked in LDS so phase 3 can index them dynamically without scratch.
__global__ __launch_bounds__(1024) void plan_k(const int* __restrict__ top_i,
                                               int* __restrict__ eoff,
                                               int* __restrict__ tok_list,
                                               int* __restrict__ slot_of) {
  const int tid = threadIdx.x;
  const int lane = tid & 63, wid = tid >> 6;  // 16 waves
  __shared__ int ws[16][EXPERTS];   // per-wave totals -> per-wave bases
  __shared__ int eoff_s[EXPERTS];
  __shared__ int base_lds[1024 * EXPERTS];  // 32 KB

  int ids[16];
  unsigned long long h64 = 0;
#pragma unroll
  for (int j = 0; j < 16; ++j) {
    ids[j] = top_i[tid * 16 + j];
    h64 += 1ull << (ids[j] * 8);
  }
#pragma unroll
  for (int e = 0; e < EXPERTS; ++e) {
    const int h = (int)((h64 >> (8 * e)) & 0xff);
    int v = h;
    for (int s = 1; s < 64; s <<= 1) {
      const int u = __shfl_up(v, s);
      if (lane >= s) v += u;
    }
    const int excl = v - h;
    const int tot = __shfl(v, 63);
    if (lane == 0) ws[wid][e] = tot;
    base_lds[tid * EXPERTS + e] = excl;  // wave/global bases added below
  }
  __syncthreads();
  if (tid == 0) {
    int tot[EXPERTS];
    for (int e = 0; e < EXPERTS; ++e) {
      int run = 0;
      for (int w = 0; w < 16; ++w) { const int c = ws[w][e]; ws[w][e] = run; run += c; }
      tot[e] = run;
    }
    int s = 0;
    for (int e = 0; e < EXPERTS; ++e) { eoff_s[e] = s; eoff[e] = s; s += tot[e]; }
    eoff[EXPERTS] = s;  // == NSLOT
  }
  __syncthreads();
#pragma unroll
  for (int e = 0; e < EXPERTS; ++e)
    base_lds[tid * EXPERTS + e] += eoff_s[e] + ws[wid][e];
  // phase 3: assign slots in entry order (stable)
  unsigned long long pre64 = 0;
#pragma unroll
  for (int j = 0; j < 16; ++j) {
    const int entry = tid * 16 + j;
    const int e = ids[j];
    const int pre = (int)((pre64 >> (8 * e)) & 0xff);
    pre64 += 1ull << (8 * e);
    const int s = base_lds[tid * EXPERTS + e] + pre;
    tok_list[s] = entry >> 1;  // token index
    slot_of[entry] = s;
  }
}

// ---------------------------------------------------------------------------
// Per-expert GEMM, m97-style: 128x128 tile, BK=32, mfma_f32_16x16x32_bf16,
// global_load_lds(16B) staging, LDS tiles stored k-contiguous.
//   C[m][n] = act( sum_k A[row(m)][k] * W[e][n][k] + bias[e][n] )
// GATHER: A row = tok_list[off+m] (x rows); else A row = off+m (h buffers).
template <int GATHER, int LEAKY, int OUTBF>
__global__ __launch_bounds__(256) void moe_gemm(
    const __bf16* __restrict__ A, const int* __restrict__ tok,
    const __bf16* __restrict__ W, const float* __restrict__ bias,
    const int* __restrict__ eoff, __bf16* __restrict__ outb,
    float* __restrict__ outf) {
  const int e = blockIdx.z;
  const int off = eoff[e];
  const int ne = eoff[e + 1] - off;
  const int m0 = blockIdx.y * 128;
  if (m0 >= ne) return;
  const int n0 = blockIdx.x * 128;

  __shared__ __align__(16) __bf16 As[128 * 32];  // [row][k]
  __shared__ __align__(16) __bf16 Bs[128 * 32];  // [n][k]

  const int tid = threadIdx.x;
  const int lane = tid & 63;
  const int wid = tid >> 6;
  const int wm = wid >> 1, wn = wid & 1;
  const int ln = lane & 15, quad = lane >> 4;

  // Staging pointers: chunk c covers tile row c>>2, k-chunk (c&3)*8.
  const __bf16* aptr[2];
  const __bf16* bptr[2];
  __bf16* alds[2];
  __bf16* blds[2];
#pragma unroll
  for (int j = 0; j < 2; ++j) {
    const int c = (wid * 2 + j) * 64 + lane;  // 0..511
    const int row = c >> 2, kc = c & 3;
    int r = m0 + row;
    if (r >= ne) r = m0;  // clamp: garbage rows computed but never stored
    const long arow = GATHER ? (long)tok[off + r] : (long)(off + r);
    aptr[j] = A + arow * DDIM + kc * 8;
    alds[j] = (__bf16*)As + (wid * 2 + j) * 512;
    bptr[j] = W + ((long)e << 20) + (long)(n0 + row) * 1024 + kc * 8;
    blds[j] = (__bf16*)Bs + (wid * 2 + j) * 512;
  }

  const f32x4_t vzero = {0.f, 0.f, 0.f, 0.f};
  f32x4_t acc[4][4];
#pragma unroll
  for (int i = 0; i < 4; ++i)
#pragma unroll
    for (int j = 0; j < 4; ++j) acc[i][j] = vzero;

  for (int kt = 0; kt < 32; ++kt) {
    const int k0 = kt * 32;
    __syncthreads();  // previous iter's LDS reads done
    gl_lds16(aptr[0] + k0, alds[0]);
    gl_lds16(aptr[1] + k0, alds[1]);
    gl_lds16(bptr[0] + k0, blds[0]);
    gl_lds16(bptr[1] + k0, blds[1]);
    __syncthreads();  // drains vmcnt: staged data visible

    bf16x8_t aF[4], bF[4];
#pragma unroll
    for (int i = 0; i < 4; ++i)
      aF[i] = *(const bf16x8_t*)(As + (wm * 64 + i * 16 + ln) * 32 + quad * 8);
#pragma unroll
    for (int j = 0; j < 4; ++j)
      bF[j] = *(const bf16x8_t*)(Bs + (wn * 64 + j * 16 + ln) * 32 + quad * 8);
#pragma unroll
    for (int i = 0; i < 4; ++i)
#pragma unroll
      for (int j = 0; j < 4; ++j)
        acc[i][j] = __builtin_amdgcn_mfma_f32_16x16x32_bf16(aF[i], bF[j],
                                                            acc[i][j], 0, 0, 0);
  }

  // Epilogue. C/D layout: col = lane&15, row = quad*4 + reg.
  const float* bs = bias + e * 1024;
#pragma unroll
  for (int i = 0; i < 4; ++i) {
    const int rloc = wm * 64 + i * 16 + quad * 4;
#pragma unroll
    for (int j = 0; j < 4; ++j) {
      const int col = n0 + wn * 64 + j * 16 + ln;
      const float bv = bs[col];
#pragma unroll
      for (int r = 0; r < 4; ++r) {
        const int m = m0 + rloc + r;
        if (m < ne) {
          float v = acc[i][j][r] + bv;
          if (LEAKY) v = (v >= 0.f) ? v : 0.01f * v;
          if (OUTBF)
            outb[(size_t)(off + m) * 1024 + col] = (__bf16)v;
          else
            outf[(size_t)(off + m) * 1024 + col] = v;
        }
      }
    }
  }
}

// ---------------------------------------------------------------------------
// Final combine: out[t] = wA*eo[slotA] + wB*eo[slotB]
__global__ __launch_bounds__(256) void combine_k(
    const float* __restrict__ eo, const int* __restrict__ slot_of,
    const float* __restrict__ top_w, float* __restrict__ out) {
  const int t = blockIdx.x;
  const int s1 = slot_of[t * 2], s2 = slot_of[t * 2 + 1];
  const float w1 = top_w[t * 2], w2 = top_w[t * 2 + 1];
  const float4 a = ((const float4*)(eo + (size_t)s1 * DDIM))[threadIdx.x];
  const float4 b = ((const float4*)(eo + (size_t)s2 * DDIM))[threadIdx.x];
  float4 o;
  o.x = w1 * a.x + w2 * b.x;
  o.y = w1 * a.y + w2 * b.y;
  o.z = w1 * a.z + w2 * b.z;
  o.w = w1 * a.w + w2 * b.w;
  ((float4*)(out + (size_t)t * DDIM))[threadIdx.x] = o;
}

// ---------------------------------------------------------------------------
extern "C" void kernel_launch(void* const* d_in, const int* in_sizes, int n_in,
                              void* d_out, int out_size, void* d_ws,
                              size_t ws_size, hipStream_t stream) {
  (void)in_sizes; (void)n_in; (void)out_size; (void)ws_size;
  const float* x  = (const float*)d_in[0];
  const float* gw = (const float*)d_in[1];
  const float* gb = (const float*)d_in[2];
  const float* w1 = (const float*)d_in[3];
  const float* b1 = (const float*)d_in[4];
  const float* w2 = (const float*)d_in[5];
  const float* b2 = (const float*)d_in[6];
  const float* w3 = (const float*)d_in[7];
  const float* b3 = (const float*)d_in[8];
  float* out = (float*)d_out;

  // Workspace carve-up (~202 MB total).
  uint8_t* p = (uint8_t*)d_ws;
  auto alloc = [&](size_t b) {
    uint8_t* r = p;
    p += (b + 255) & ~(size_t)255;
    return r;
  };
  int*    eoff     = (int*)alloc(4 * (EXPERTS + 1));
  int*    top_i    = (int*)alloc(4ull * TOKENS * 2);
  float*  top_w    = (float*)alloc(4ull * TOKENS * 2);
  int*    slot_of  = (int*)alloc(4ull * TOKENS * 2);
  int*    tok_list = (int*)alloc(4ull * NSLOT);
  __bf16* xbf      = (__bf16*)alloc(2ull * TOKENS * DDIM);
  __bf16* w1T      = (__bf16*)alloc(2ull * EXPERTS * 1024 * 1024);
  __bf16* w2T      = (__bf16*)alloc(2ull * EXPERTS * 1024 * 1024);
  __bf16* w3T      = (__bf16*)alloc(2ull * EXPERTS * 1024 * 1024);
  __bf16* h1       = (__bf16*)alloc(2ull * NSLOT * 1024);
  __bf16* h2       = (__bf16*)alloc(2ull * NSLOT * 1024);
  float*  eo       = (float*)alloc(4ull * NSLOT * 1024);

  gate_k<<<TOKENS / 4, 256, 0, stream>>>(x, gw, gb, xbf, top_i, top_w);
  twt_k<<<dim3(16, 32, EXPERTS), dim3(32, 8), 0, stream>>>(w1, w1T);
  twt_k<<<dim3(16, 32, EXPERTS), dim3(32, 8), 0, stream>>>(w2, w2T);
  twt_k<<<dim3(16, 32, EXPERTS), dim3(32, 8), 0, stream>>>(w3, w3T);
  plan_k<<<1, 1024, 0, stream>>>(top_i, eoff, tok_list, slot_of);

  // 3 expert-parallel GEMM layers; grid.y sized for worst-case routing.
  moe_gemm<1, 1, 1><<<dim3(8, 64, EXPERTS), 256, 0, stream>>>(
      xbf, tok_list, w1T, b1, eoff, h1, nullptr);
  moe_gemm<0, 1, 1><<<dim3(8, 64, EXPERTS), 256, 0, stream>>>(
      h1, nullptr, w2T, b2, eoff, h2, nullptr);
  moe_gemm<0, 0, 0><<<dim3(8, 64, EXPERTS), 256, 0, stream>>>(
      h2, nullptr, w3T, b3, eoff, nullptr, eo);

  combine_k<<<TOKENS, 256, 0, stream>>>(eo, slot_of, top_w, out);
}